// Round 1
// baseline (606.254 us; speedup 1.0000x reference)
//
#include <hip/hip_runtime.h>
#include <hip/hip_bf16.h>
#include <cstdint>

typedef __attribute__((ext_vector_type(8))) __bf16 bf16x8;
typedef __attribute__((ext_vector_type(4))) __bf16 bf16x4;
typedef __attribute__((ext_vector_type(4))) float f32x4;

#define MFMA16(a, b, c) __builtin_amdgcn_mfma_f32_16x16x32_bf16(a, b, c, 0, 0, 0)

// Problem constants
static constexpr int Bb = 4, Ss = 2048, Dd = 1024, Hh = 16, HDc = 64;
static constexpr int Mrows = Bb * Ss;  // 8192

// ---------------------------------------------------------------------------
// GEMM1: qkv = x @ w_qkv + b_qkv ; scatter to Q[B,H,S,64], K[B,H,S,64],
// Vt[B,H,64,S] all bf16.  M=8192, N=3072, K=1024.
// ---------------------------------------------------------------------------
__global__ __launch_bounds__(256) void qkv_gemm(
    const float* __restrict__ X, const float* __restrict__ W,
    const float* __restrict__ bias,
    __bf16* __restrict__ Qb, __bf16* __restrict__ Kb, __bf16* __restrict__ Vt)
{
  __shared__ __bf16 a_sh[128 * 40];
  __shared__ __bf16 b_sh[128 * 40];
  const int n0 = blockIdx.x * 128;
  const int m0 = blockIdx.y * 128;
  const int t = threadIdx.x;
  const int wave = t >> 6, lane = t & 63;
  const int r = lane & 15, g = lane >> 4;
  const int wm = (wave >> 1) * 64, wn = (wave & 1) * 64;

  f32x4 acc[4][4] = {};

  for (int k0 = 0; k0 < 1024; k0 += 32) {
    __syncthreads();
    // Stage A tile 128x32 (f32 -> bf16)
    {
      const int tr = t >> 3;            // 0..31
      const int tc = (t & 7) * 4;       // 0..28
      #pragma unroll
      for (int p = 0; p < 4; ++p) {
        const int row = p * 32 + tr;
        const float4 v = *(const float4*)(X + (m0 + row) * 1024 + k0 + tc);
        bf16x4 hh = { (__bf16)v.x, (__bf16)v.y, (__bf16)v.z, (__bf16)v.w };
        *(bf16x4*)&a_sh[row * 40 + tc] = hh;
      }
    }
    // Stage B tile 32x128 transposed into b_sh[n][k]
    {
      const int nn = t & 127, kg = t >> 7;  // kg in {0,1}
      bf16x8 h0, h1;
      #pragma unroll
      for (int j = 0; j < 8; ++j)
        h0[j] = (__bf16)W[(k0 + kg * 16 + j) * 3072 + n0 + nn];
      #pragma unroll
      for (int j = 0; j < 8; ++j)
        h1[j] = (__bf16)W[(k0 + kg * 16 + 8 + j) * 3072 + n0 + nn];
      *(bf16x8*)&b_sh[nn * 40 + kg * 16] = h0;
      *(bf16x8*)&b_sh[nn * 40 + kg * 16 + 8] = h1;
    }
    __syncthreads();

    bf16x8 af[4], bfr[4];
    #pragma unroll
    for (int i = 0; i < 4; ++i)
      af[i] = *(bf16x8*)&a_sh[(wm + i * 16 + r) * 40 + g * 8];
    #pragma unroll
    for (int j = 0; j < 4; ++j)
      bfr[j] = *(bf16x8*)&b_sh[(wn + j * 16 + r) * 40 + g * 8];
    #pragma unroll
    for (int i = 0; i < 4; ++i)
      #pragma unroll
      for (int j = 0; j < 4; ++j)
        acc[i][j] = MFMA16(af[i], bfr[j], acc[i][j]);
  }

  // Epilogue: add bias, scatter to Q / K / Vt (bf16)
  const int which = n0 >> 10;  // 0=Q, 1=K, 2=V  (whole 128-tile is inside one)
  #pragma unroll
  for (int j = 0; j < 4; ++j) {
    const int nc = n0 + wn + j * 16 + r;
    const float bv = bias[nc];
    const int hh = (nc & 1023) >> 6;
    const int d = nc & 63;
    #pragma unroll
    for (int i = 0; i < 4; ++i) {
      #pragma unroll
      for (int rr = 0; rr < 4; ++rr) {
        const int mr = m0 + wm + i * 16 + g * 4 + rr;
        const int bb = mr >> 11;       // / 2048
        const int ss = mr & 2047;
        const __bf16 val = (__bf16)(acc[i][j][rr] + bv);
        if (which == 0)
          Qb[((bb * 16 + hh) * 2048 + ss) * 64 + d] = val;
        else if (which == 1)
          Kb[((bb * 16 + hh) * 2048 + ss) * 64 + d] = val;
        else
          Vt[((bb * 16 + hh) * 64 + d) * 2048 + ss] = val;
      }
    }
  }
}

// ---------------------------------------------------------------------------
// Flash attention: one block = one (b,h,qtile of 64 rows); 4 waves x 16 rows.
// K read from global (L2-resident), V read from transposed Vt (contiguous
// B-fragments).  P staged via small per-wave LDS tile.
// ---------------------------------------------------------------------------
__global__ __launch_bounds__(256) void attn_kernel(
    const __bf16* __restrict__ Q, const __bf16* __restrict__ K,
    const __bf16* __restrict__ Vt, __bf16* __restrict__ AO)
{
  __shared__ __bf16 p_sh[4][16][72];   // per-wave P tile, stride 72 (16B-aligned rows)
  const int b = blockIdx.z, h = blockIdx.y, qt = blockIdx.x;
  const int t = threadIdx.x, wave = t >> 6, lane = t & 63;
  const int r = lane & 15, g = lane >> 4;

  const __bf16* Qp = Q + ((b * 16 + h) * 2048) * 64;
  const __bf16* Kp = K + ((b * 16 + h) * 2048) * 64;
  const __bf16* Vp = Vt + ((b * 16 + h) * 64) * 2048;
  const int q0 = qt * 64 + wave * 16;

  const bf16x8 qf0 = *(const bf16x8*)(Qp + (q0 + r) * 64 + g * 8);
  const bf16x8 qf1 = *(const bf16x8*)(Qp + (q0 + r) * 64 + 32 + g * 8);

  float mrun[4], lrun[4];
  f32x4 o[4] = {};
  #pragma unroll
  for (int rr = 0; rr < 4; ++rr) { mrun[rr] = -1e30f; lrun[rr] = 0.f; }

  for (int k0 = 0; k0 < 2048; k0 += 64) {
    // --- scores: S^tile [16q x 64k], per 16-col subtile kt ---
    f32x4 sacc[4];
    #pragma unroll
    for (int kt = 0; kt < 4; ++kt) {
      const bf16x8 kf0 = *(const bf16x8*)(Kp + (k0 + kt * 16 + r) * 64 + g * 8);
      const bf16x8 kf1 = *(const bf16x8*)(Kp + (k0 + kt * 16 + r) * 64 + 32 + g * 8);
      f32x4 s = {};
      s = MFMA16(qf0, kf0, s);
      s = MFMA16(qf1, kf1, s);
      sacc[kt] = s;
    }
    #pragma unroll
    for (int kt = 0; kt < 4; ++kt)
      #pragma unroll
      for (int rr = 0; rr < 4; ++rr) sacc[kt][rr] *= 0.125f;  // 1/sqrt(64)

    // --- online softmax (rows live in 16-lane groups; xor 1,2,4,8) ---
    float mnew[4], alpha[4];
    #pragma unroll
    for (int rr = 0; rr < 4; ++rr) {
      float v = fmaxf(fmaxf(sacc[0][rr], sacc[1][rr]),
                      fmaxf(sacc[2][rr], sacc[3][rr]));
      v = fmaxf(v, __shfl_xor(v, 1));
      v = fmaxf(v, __shfl_xor(v, 2));
      v = fmaxf(v, __shfl_xor(v, 4));
      v = fmaxf(v, __shfl_xor(v, 8));
      mnew[rr] = fmaxf(mrun[rr], v);
      alpha[rr] = __expf(mrun[rr] - mnew[rr]);
      mrun[rr] = mnew[rr];
    }

    // ensure previous iteration's P reads are done before overwriting
    asm volatile("s_waitcnt lgkmcnt(0)" ::: "memory");

    float psum[4] = {0.f, 0.f, 0.f, 0.f};
    #pragma unroll
    for (int kt = 0; kt < 4; ++kt)
      #pragma unroll
      for (int rr = 0; rr < 4; ++rr) {
        const float p = __expf(sacc[kt][rr] - mnew[rr]);
        psum[rr] += p;
        p_sh[wave][g * 4 + rr][kt * 16 + r] = (__bf16)p;
      }
    #pragma unroll
    for (int rr = 0; rr < 4; ++rr) {
      float v = psum[rr];
      v += __shfl_xor(v, 1);
      v += __shfl_xor(v, 2);
      v += __shfl_xor(v, 4);
      v += __shfl_xor(v, 8);
      lrun[rr] = lrun[rr] * alpha[rr] + v;
    }
    #pragma unroll
    for (int dt = 0; dt < 4; ++dt)
      #pragma unroll
      for (int rr = 0; rr < 4; ++rr) o[dt][rr] *= alpha[rr];

    // make P visible to all lanes of this wave
    asm volatile("s_waitcnt lgkmcnt(0)" ::: "memory");
    __builtin_amdgcn_sched_barrier(0);

    // --- PV: O += P @ V  (A-frag from p_sh, B-frag contiguous from Vt) ---
    #pragma unroll
    for (int c = 0; c < 2; ++c) {
      const bf16x8 pf = *(const bf16x8*)&p_sh[wave][r][c * 32 + g * 8];
      #pragma unroll
      for (int dt = 0; dt < 4; ++dt) {
        const bf16x8 vf =
            *(const bf16x8*)(Vp + (dt * 16 + r) * 2048 + k0 + c * 32 + g * 8);
        o[dt] = MFMA16(pf, vf, o[dt]);
      }
    }
  }

  // epilogue: normalize, write attn_out[b, s, h*64+d] bf16
  #pragma unroll
  for (int rr = 0; rr < 4; ++rr) {
    const float inv = 1.0f / lrun[rr];
    const int ss = q0 + g * 4 + rr;
    #pragma unroll
    for (int dt = 0; dt < 4; ++dt) {
      AO[(b * 2048 + ss) * 1024 + h * 64 + dt * 16 + r] =
          (__bf16)(o[dt][rr] * inv);
    }
  }
}

// ---------------------------------------------------------------------------
// GEMM2: out = attn_out(bf16) @ w_proj + b_proj ; M=8192, N=1024, K=1024,
// f32 output.
// ---------------------------------------------------------------------------
__global__ __launch_bounds__(256) void proj_gemm(
    const __bf16* __restrict__ A, const float* __restrict__ W,
    const float* __restrict__ bias, float* __restrict__ out)
{
  __shared__ __bf16 a_sh[128 * 40];
  __shared__ __bf16 b_sh[128 * 40];
  const int n0 = blockIdx.x * 128;
  const int m0 = blockIdx.y * 128;
  const int t = threadIdx.x;
  const int wave = t >> 6, lane = t & 63;
  const int r = lane & 15, g = lane >> 4;
  const int wm = (wave >> 1) * 64, wn = (wave & 1) * 64;

  f32x4 acc[4][4] = {};

  for (int k0 = 0; k0 < 1024; k0 += 32) {
    __syncthreads();
    // Stage A tile 128x32 (already bf16): 16B per thread x 2 passes
    {
      const int tr = t >> 2;            // 0..63
      const int tc = (t & 3) * 8;       // 0,8,16,24
      #pragma unroll
      for (int p = 0; p < 2; ++p) {
        const int row = p * 64 + tr;
        const bf16x8 v = *(const bf16x8*)(A + (m0 + row) * 1024 + k0 + tc);
        *(bf16x8*)&a_sh[row * 40 + tc] = v;
      }
    }
    // Stage B tile 32x128 transposed into b_sh[n][k]
    {
      const int nn = t & 127, kg = t >> 7;
      bf16x8 h0, h1;
      #pragma unroll
      for (int j = 0; j < 8; ++j)
        h0[j] = (__bf16)W[(k0 + kg * 16 + j) * 1024 + n0 + nn];
      #pragma unroll
      for (int j = 0; j < 8; ++j)
        h1[j] = (__bf16)W[(k0 + kg * 16 + 8 + j) * 1024 + n0 + nn];
      *(bf16x8*)&b_sh[nn * 40 + kg * 16] = h0;
      *(bf16x8*)&b_sh[nn * 40 + kg * 16 + 8] = h1;
    }
    __syncthreads();

    bf16x8 af[4], bfr[4];
    #pragma unroll
    for (int i = 0; i < 4; ++i)
      af[i] = *(bf16x8*)&a_sh[(wm + i * 16 + r) * 40 + g * 8];
    #pragma unroll
    for (int j = 0; j < 4; ++j)
      bfr[j] = *(bf16x8*)&b_sh[(wn + j * 16 + r) * 40 + g * 8];
    #pragma unroll
    for (int i = 0; i < 4; ++i)
      #pragma unroll
      for (int j = 0; j < 4; ++j)
        acc[i][j] = MFMA16(af[i], bfr[j], acc[i][j]);
  }

  // Epilogue: f32 out + bias
  #pragma unroll
  for (int j = 0; j < 4; ++j) {
    const int nc = n0 + wn + j * 16 + r;
    const float bv = bias[nc];
    #pragma unroll
    for (int i = 0; i < 4; ++i) {
      #pragma unroll
      for (int rr = 0; rr < 4; ++rr) {
        const int mr = m0 + wm + i * 16 + g * 4 + rr;
        out[mr * 1024 + nc] = acc[i][j][rr] + bv;
      }
    }
  }
}

// ---------------------------------------------------------------------------
extern "C" void kernel_launch(void* const* d_in, const int* in_sizes, int n_in,
                              void* d_out, int out_size, void* d_ws, size_t ws_size,
                              hipStream_t stream) {
  (void)in_sizes; (void)n_in; (void)out_size; (void)ws_size;
  const float* x      = (const float*)d_in[0];
  const float* w_qkv  = (const float*)d_in[1];
  const float* b_qkv  = (const float*)d_in[2];
  const float* w_proj = (const float*)d_in[3];
  const float* b_proj = (const float*)d_in[4];
  float* out = (float*)d_out;

  const size_t elems = (size_t)Mrows * 1024;  // 8.4M bf16 per buffer
  __bf16* Qb = (__bf16*)d_ws;
  __bf16* Kb = Qb + elems;
  __bf16* Vt = Kb + elems;
  __bf16* AO = Vt + elems;

  qkv_gemm<<<dim3(24, 64), 256, 0, stream>>>(x, w_qkv, b_qkv, Qb, Kb, Vt);
  attn_kernel<<<dim3(32, 16, 4), 256, 0, stream>>>(Qb, Kb, Vt, AO);
  proj_gemm<<<dim3(8, 64), 256, 0, stream>>>(AO, w_proj, b_proj, out);
}

// Round 2
// 311.396 us; speedup vs baseline: 1.9469x; 1.9469x over previous
//
#include <hip/hip_runtime.h>
#include <hip/hip_bf16.h>
#include <cstdint>

typedef __attribute__((ext_vector_type(8))) __bf16 bf16x8;
typedef __attribute__((ext_vector_type(4))) __bf16 bf16x4;
typedef __attribute__((ext_vector_type(4))) float f32x4;

#define MFMA16(a, b, c) __builtin_amdgcn_mfma_f32_16x16x32_bf16(a, b, c, 0, 0, 0)

// Problem constants
static constexpr int Bb = 4, Ss = 2048, Dd = 1024, Hh = 16, HDc = 64;
static constexpr int Mrows = Bb * Ss;  // 8192

// ---------------------------------------------------------------------------
// GEMM1: qkv = x @ w_qkv + b_qkv ; scatter to Q[B,H,S,64], K[B,H,S,64],
// Vt[B,H,64,S] all bf16.  M=8192, N=3072, K=1024.
// ---------------------------------------------------------------------------
__global__ __launch_bounds__(256) void qkv_gemm(
    const float* __restrict__ X, const float* __restrict__ W,
    const float* __restrict__ bias,
    __bf16* __restrict__ Qb, __bf16* __restrict__ Kb, __bf16* __restrict__ Vt)
{
  __shared__ __bf16 a_sh[128 * 40];
  __shared__ __bf16 b_sh[128 * 40];
  const int n0 = blockIdx.x * 128;
  const int m0 = blockIdx.y * 128;
  const int t = threadIdx.x;
  const int wave = t >> 6, lane = t & 63;
  const int r = lane & 15, g = lane >> 4;
  const int wm = (wave >> 1) * 64, wn = (wave & 1) * 64;

  f32x4 acc[4][4] = {};

  for (int k0 = 0; k0 < 1024; k0 += 32) {
    __syncthreads();
    // Stage A tile 128x32 (f32 -> bf16)
    {
      const int tr = t >> 3;            // 0..31
      const int tc = (t & 7) * 4;       // 0..28
      #pragma unroll
      for (int p = 0; p < 4; ++p) {
        const int row = p * 32 + tr;
        const float4 v = *(const float4*)(X + (m0 + row) * 1024 + k0 + tc);
        bf16x4 hh = { (__bf16)v.x, (__bf16)v.y, (__bf16)v.z, (__bf16)v.w };
        *(bf16x4*)&a_sh[row * 40 + tc] = hh;
      }
    }
    // Stage B tile 32x128 transposed into b_sh[n][k]
    {
      const int nn = t & 127, kg = t >> 7;  // kg in {0,1}
      bf16x8 h0, h1;
      #pragma unroll
      for (int j = 0; j < 8; ++j)
        h0[j] = (__bf16)W[(k0 + kg * 16 + j) * 3072 + n0 + nn];
      #pragma unroll
      for (int j = 0; j < 8; ++j)
        h1[j] = (__bf16)W[(k0 + kg * 16 + 8 + j) * 3072 + n0 + nn];
      *(bf16x8*)&b_sh[nn * 40 + kg * 16] = h0;
      *(bf16x8*)&b_sh[nn * 40 + kg * 16 + 8] = h1;
    }
    __syncthreads();

    bf16x8 af[4], bfr[4];
    #pragma unroll
    for (int i = 0; i < 4; ++i)
      af[i] = *(bf16x8*)&a_sh[(wm + i * 16 + r) * 40 + g * 8];
    #pragma unroll
    for (int j = 0; j < 4; ++j)
      bfr[j] = *(bf16x8*)&b_sh[(wn + j * 16 + r) * 40 + g * 8];
    #pragma unroll
    for (int i = 0; i < 4; ++i)
      #pragma unroll
      for (int j = 0; j < 4; ++j)
        acc[i][j] = MFMA16(af[i], bfr[j], acc[i][j]);
  }

  // Epilogue: add bias, scatter to Q / K / Vt (bf16)
  const int which = n0 >> 10;  // 0=Q, 1=K, 2=V  (whole 128-tile is inside one)
  #pragma unroll
  for (int j = 0; j < 4; ++j) {
    const int nc = n0 + wn + j * 16 + r;
    const float bv = bias[nc];
    const int hh = (nc & 1023) >> 6;
    const int d = nc & 63;
    #pragma unroll
    for (int i = 0; i < 4; ++i) {
      #pragma unroll
      for (int rr = 0; rr < 4; ++rr) {
        const int mr = m0 + wm + i * 16 + g * 4 + rr;
        const int bb = mr >> 11;       // / 2048
        const int ss = mr & 2047;
        const __bf16 val = (__bf16)(acc[i][j][rr] + bv);
        if (which == 0)
          Qb[((bb * 16 + hh) * 2048 + ss) * 64 + d] = val;
        else if (which == 1)
          Kb[((bb * 16 + hh) * 2048 + ss) * 64 + d] = val;
        else
          Vt[((bb * 16 + hh) * 64 + d) * 2048 + ss] = val;
      }
    }
  }
}

// ---------------------------------------------------------------------------
// Flash attention, swapped-QK^T form.
// Block = 128 q-rows of one (b,h); 4 waves x 32 q-rows (2 x 16-row subtiles).
// K,V tiles (64 keys) staged in LDS shared by the 4 waves.
// QK^T computed as mfma(K, Q) -> lane holds S^T[k][q=lane&15]; softmax row
// ops are 2 shfl_xor; P stays in registers.
// PV uses a per-32-block column permutation pi(g,j)=16*(j>>2)+4g+(j&3)
// applied to BOTH operands (V staged permuted in LDS; P packed lane-local)
// so the contraction is unchanged but needs no cross-lane P movement.
// ---------------------------------------------------------------------------
__global__ __launch_bounds__(256) void attn_kernel(
    const __bf16* __restrict__ Q, const __bf16* __restrict__ K,
    const __bf16* __restrict__ Vt, __bf16* __restrict__ AO)
{
  __shared__ __bf16 k_sh[64][72];
  __shared__ __bf16 v_sh[64][72];
  const int b = blockIdx.z, h = blockIdx.y, qt = blockIdx.x;
  const int t = threadIdx.x, wave = t >> 6, lane = t & 63;
  const int r = lane & 15, g = lane >> 4;

  const __bf16* Qp = Q + ((b * 16 + h) * 2048) * 64;
  const __bf16* Kp = K + ((b * 16 + h) * 2048) * 64;
  const __bf16* Vp = Vt + ((b * 16 + h) * 64) * 2048;
  const int q0 = qt * 128 + wave * 32;

  // Q fragments for the wave's 2 q-subtiles x 2 head-dim halves
  bf16x8 qf[2][2];
  #pragma unroll
  for (int qh = 0; qh < 2; ++qh)
    #pragma unroll
    for (int hh = 0; hh < 2; ++hh)
      qf[qh][hh] = *(const bf16x8*)(Qp + (q0 + qh * 16 + r) * 64 + hh * 32 + g * 8);

  float mrun[2] = {-1e30f, -1e30f};
  float lrun[2] = {0.f, 0.f};
  f32x4 o[4][2] = {};  // o[dt][qh]: lane holds O[q=r][d=dt*16+4g+rr]

  const float SC = 0.18033688f;  // (1/sqrt(64)) * log2(e)

  // staging indices (computed once)
  const int krow = t >> 3, kcol = (t & 7) * 8;        // K: 16B chunks
  const int vch = t & 15;                             // V: 8B chunks
  const int vcol = 32 * (vch >> 3) + 8 * (vch & 3) + 4 * ((vch >> 2) & 1);

  for (int k0 = 0; k0 < 2048; k0 += 64) {
    __syncthreads();
    // --- stage K tile [64 keys][64 d] ---
    *(bf16x8*)&k_sh[krow][kcol] =
        *(const bf16x8*)(Kp + (k0 + krow) * 64 + kcol);
    *(bf16x8*)&k_sh[krow + 32][kcol] =
        *(const bf16x8*)(Kp + (k0 + krow + 32) * 64 + kcol);
    // --- stage V tile [64 d][64 keys], columns permuted by pi ---
    #pragma unroll
    for (int p = 0; p < 4; ++p) {
      const int row = p * 16 + (t >> 4);
      *(bf16x4*)&v_sh[row][vcol] =
          *(const bf16x4*)(Vp + row * 2048 + k0 + 4 * vch);
    }
    __syncthreads();

    // --- QK^T (swapped): sacc[kt][qh] holds S^T[k=16kt+4g+rr][q=r] ---
    f32x4 sacc[4][2];
    #pragma unroll
    for (int kt = 0; kt < 4; ++kt) {
      const bf16x8 kf0 = *(const bf16x8*)&k_sh[kt * 16 + r][g * 8];
      const bf16x8 kf1 = *(const bf16x8*)&k_sh[kt * 16 + r][32 + g * 8];
      #pragma unroll
      for (int qh = 0; qh < 2; ++qh) {
        f32x4 s = {};
        s = MFMA16(kf0, qf[qh][0], s);
        s = MFMA16(kf1, qf[qh][1], s);
        sacc[kt][qh] = s;
      }
    }

    // --- online softmax (per q-subtile); P packed lane-local into pf ---
    bf16x8 pf[2][2];
    #pragma unroll
    for (int qh = 0; qh < 2; ++qh) {
      float tm = sacc[0][qh][0];
      #pragma unroll
      for (int kt = 0; kt < 4; ++kt)
        #pragma unroll
        for (int rr = 0; rr < 4; ++rr)
          tm = fmaxf(tm, sacc[kt][qh][rr]);
      tm = fmaxf(tm, __shfl_xor(tm, 16));
      tm = fmaxf(tm, __shfl_xor(tm, 32));
      const float mnew = fmaxf(mrun[qh], tm);
      const float al = exp2f((mrun[qh] - mnew) * SC);
      mrun[qh] = mnew;

      float pv[4][4];
      float ps = 0.f;
      #pragma unroll
      for (int kt = 0; kt < 4; ++kt)
        #pragma unroll
        for (int rr = 0; rr < 4; ++rr) {
          const float p = exp2f((sacc[kt][qh][rr] - mnew) * SC);
          pv[kt][rr] = p;
          ps += p;
        }
      ps += __shfl_xor(ps, 16);
      ps += __shfl_xor(ps, 32);
      lrun[qh] = lrun[qh] * al + ps;

      // pf[qh][c][j] = P at k = 32c + 16*(j>>2) + 4g + (j&3)  (pi order)
      #pragma unroll
      for (int c = 0; c < 2; ++c)
        #pragma unroll
        for (int j = 0; j < 8; ++j)
          pf[qh][c][j] = (__bf16)pv[2 * c + (j >> 2)][j & 3];

      #pragma unroll
      for (int dt = 0; dt < 4; ++dt)
        #pragma unroll
        for (int rr = 0; rr < 4; ++rr)
          o[dt][qh][rr] *= al;
    }

    // --- PV: O^T accumulate, A = V (pi-permuted), B = P (pi-packed) ---
    #pragma unroll
    for (int c = 0; c < 2; ++c)
      #pragma unroll
      for (int dt = 0; dt < 4; ++dt) {
        const bf16x8 vf = *(const bf16x8*)&v_sh[dt * 16 + r][c * 32 + g * 8];
        o[dt][0] = MFMA16(vf, pf[0][c], o[dt][0]);
        o[dt][1] = MFMA16(vf, pf[1][c], o[dt][1]);
      }
  }

  // --- epilogue: normalize, write AO[b, s, h*64+d] (d = dt*16+4g+rr) ---
  #pragma unroll
  for (int qh = 0; qh < 2; ++qh) {
    const float inv = 1.0f / lrun[qh];
    const int ss = q0 + qh * 16 + r;
    #pragma unroll
    for (int dt = 0; dt < 4; ++dt) {
      bf16x4 ov;
      #pragma unroll
      for (int rr = 0; rr < 4; ++rr)
        ov[rr] = (__bf16)(o[dt][qh][rr] * inv);
      *(bf16x4*)&AO[(b * 2048 + ss) * 1024 + h * 64 + dt * 16 + 4 * g] = ov;
    }
  }
}

// ---------------------------------------------------------------------------
// GEMM2: out = attn_out(bf16) @ w_proj + b_proj ; M=8192, N=1024, K=1024,
// f32 output.
// ---------------------------------------------------------------------------
__global__ __launch_bounds__(256) void proj_gemm(
    const __bf16* __restrict__ A, const float* __restrict__ W,
    const float* __restrict__ bias, float* __restrict__ out)
{
  __shared__ __bf16 a_sh[128 * 40];
  __shared__ __bf16 b_sh[128 * 40];
  const int n0 = blockIdx.x * 128;
  const int m0 = blockIdx.y * 128;
  const int t = threadIdx.x;
  const int wave = t >> 6, lane = t & 63;
  const int r = lane & 15, g = lane >> 4;
  const int wm = (wave >> 1) * 64, wn = (wave & 1) * 64;

  f32x4 acc[4][4] = {};

  for (int k0 = 0; k0 < 1024; k0 += 32) {
    __syncthreads();
    // Stage A tile 128x32 (already bf16): 16B per thread x 2 passes
    {
      const int tr = t >> 2;            // 0..63
      const int tc = (t & 3) * 8;       // 0,8,16,24
      #pragma unroll
      for (int p = 0; p < 2; ++p) {
        const int row = p * 64 + tr;
        const bf16x8 v = *(const bf16x8*)(A + (m0 + row) * 1024 + k0 + tc);
        *(bf16x8*)&a_sh[row * 40 + tc] = v;
      }
    }
    // Stage B tile 32x128 transposed into b_sh[n][k]
    {
      const int nn = t & 127, kg = t >> 7;
      bf16x8 h0, h1;
      #pragma unroll
      for (int j = 0; j < 8; ++j)
        h0[j] = (__bf16)W[(k0 + kg * 16 + j) * 1024 + n0 + nn];
      #pragma unroll
      for (int j = 0; j < 8; ++j)
        h1[j] = (__bf16)W[(k0 + kg * 16 + 8 + j) * 1024 + n0 + nn];
      *(bf16x8*)&b_sh[nn * 40 + kg * 16] = h0;
      *(bf16x8*)&b_sh[nn * 40 + kg * 16 + 8] = h1;
    }
    __syncthreads();

    bf16x8 af[4], bfr[4];
    #pragma unroll
    for (int i = 0; i < 4; ++i)
      af[i] = *(bf16x8*)&a_sh[(wm + i * 16 + r) * 40 + g * 8];
    #pragma unroll
    for (int j = 0; j < 4; ++j)
      bfr[j] = *(bf16x8*)&b_sh[(wn + j * 16 + r) * 40 + g * 8];
    #pragma unroll
    for (int i = 0; i < 4; ++i)
      #pragma unroll
      for (int j = 0; j < 4; ++j)
        acc[i][j] = MFMA16(af[i], bfr[j], acc[i][j]);
  }

  // Epilogue: f32 out + bias
  #pragma unroll
  for (int j = 0; j < 4; ++j) {
    const int nc = n0 + wn + j * 16 + r;
    const float bv = bias[nc];
    #pragma unroll
    for (int i = 0; i < 4; ++i) {
      #pragma unroll
      for (int rr = 0; rr < 4; ++rr) {
        const int mr = m0 + wm + i * 16 + g * 4 + rr;
        out[mr * 1024 + nc] = acc[i][j][rr] + bv;
      }
    }
  }
}

// ---------------------------------------------------------------------------
extern "C" void kernel_launch(void* const* d_in, const int* in_sizes, int n_in,
                              void* d_out, int out_size, void* d_ws, size_t ws_size,
                              hipStream_t stream) {
  (void)in_sizes; (void)n_in; (void)out_size; (void)ws_size;
  const float* x      = (const float*)d_in[0];
  const float* w_qkv  = (const float*)d_in[1];
  const float* b_qkv  = (const float*)d_in[2];
  const float* w_proj = (const float*)d_in[3];
  const float* b_proj = (const float*)d_in[4];
  float* out = (float*)d_out;

  const size_t elems = (size_t)Mrows * 1024;  // 8.4M bf16 per buffer
  __bf16* Qb = (__bf16*)d_ws;
  __bf16* Kb = Qb + elems;
  __bf16* Vt = Kb + elems;
  __bf16* AO = Vt + elems;

  qkv_gemm<<<dim3(24, 64), 256, 0, stream>>>(x, w_qkv, b_qkv, Qb, Kb, Vt);
  attn_kernel<<<dim3(16, 16, 4), 256, 0, stream>>>(Qb, Kb, Vt, AO);
  proj_gemm<<<dim3(8, 64), 256, 0, stream>>>(AO, w_proj, b_proj, out);
}

// Round 3
// 307.047 us; speedup vs baseline: 1.9745x; 1.0142x over previous
//
#include <hip/hip_runtime.h>
#include <hip/hip_bf16.h>
#include <cstdint>

typedef __attribute__((ext_vector_type(8))) __bf16 bf16x8;
typedef __attribute__((ext_vector_type(4))) __bf16 bf16x4;
typedef __attribute__((ext_vector_type(4))) float f32x4;

#define MFMA16(a, b, c) __builtin_amdgcn_mfma_f32_16x16x32_bf16(a, b, c, 0, 0, 0)

static constexpr float SCQ = 0.18033688f;  // (1/sqrt(64)) * log2(e)

__device__ __forceinline__ void gload16(const void* g, void* l) {
  __builtin_amdgcn_global_load_lds(
      (const __attribute__((address_space(1))) void*)g,
      (__attribute__((address_space(3))) void*)l, 16, 0, 0);
}

// ---------------------------------------------------------------------------
// conv_x: f32 [8192][1024] -> bf16 same layout
// ---------------------------------------------------------------------------
__global__ __launch_bounds__(256) void conv_x(const float* __restrict__ in,
                                              __bf16* __restrict__ out) {
  const size_t i = ((size_t)blockIdx.x * 256 + threadIdx.x) * 8;
  const float4 v0 = *(const float4*)(in + i);
  const float4 v1 = *(const float4*)(in + i + 4);
  bf16x8 o = {(__bf16)v0.x, (__bf16)v0.y, (__bf16)v0.z, (__bf16)v0.w,
              (__bf16)v1.x, (__bf16)v1.y, (__bf16)v1.z, (__bf16)v1.w};
  *(bf16x8*)(out + i) = o;
}

// ---------------------------------------------------------------------------
// conv_wt: W f32 [K][N] -> Wt bf16 [N][K]  (transpose via LDS tile)
// ---------------------------------------------------------------------------
__global__ __launch_bounds__(256) void conv_wt(const float* __restrict__ W,
                                               __bf16* __restrict__ Wt,
                                               int K, int N) {
  __shared__ float tile[64][65];
  const int nb = blockIdx.x * 64, kb = blockIdx.y * 64;
  const int t = threadIdx.x, tr = t >> 4, tc = t & 15;
  #pragma unroll
  for (int p = 0; p < 4; ++p) {
    const float4 v =
        *(const float4*)(W + (size_t)(kb + p * 16 + tr) * N + nb + tc * 4);
    tile[p * 16 + tr][tc * 4 + 0] = v.x;
    tile[p * 16 + tr][tc * 4 + 1] = v.y;
    tile[p * 16 + tr][tc * 4 + 2] = v.z;
    tile[p * 16 + tr][tc * 4 + 3] = v.w;
  }
  __syncthreads();
  #pragma unroll
  for (int p = 0; p < 4; ++p) {
    const int n = p * 16 + tr, kk = tc * 4;
    bf16x4 o = {(__bf16)tile[kk + 0][n], (__bf16)tile[kk + 1][n],
                (__bf16)tile[kk + 2][n], (__bf16)tile[kk + 3][n]};
    *(bf16x4*)(Wt + (size_t)(nb + n) * K + kb + kk) = o;
  }
}

// ---------------------------------------------------------------------------
// GEMM core (m97 structure): 128x128 tile, BK=32, global_load_lds w=16,
// linear LDS.  A bf16 [M][1024] row-major, Bt bf16 [N][1024] row-major (B^T).
// ---------------------------------------------------------------------------
// qkv: scatter epilogue -> Q (pre-scaled by SCQ), K, Vt; M=8192, N=3072
__global__ __launch_bounds__(256) void qkv_gemm_b(
    const __bf16* __restrict__ A, const __bf16* __restrict__ Bt,
    const float* __restrict__ bias,
    __bf16* __restrict__ Qb, __bf16* __restrict__ Kb, __bf16* __restrict__ Vt)
{
  __shared__ alignas(16) __bf16 a_sh[128 * 32];
  __shared__ alignas(16) __bf16 b_sh[128 * 32];
  const int n0 = blockIdx.x * 128, m0 = blockIdx.y * 128;
  const int t = threadIdx.x, wave = t >> 6, lane = t & 63;
  const int r = lane & 15, g = lane >> 4;
  const int wm = (wave >> 1) * 64, wn = (wave & 1) * 64;
  f32x4 acc[4][4] = {};

  const int srow = wave * 16 + (lane >> 2);
  const int scol = (lane & 3) * 8;
  const __bf16* gA = A + (size_t)(m0 + srow) * 1024 + scol;
  const __bf16* gB = Bt + (size_t)(n0 + srow) * 1024 + scol;
  __bf16* lA = a_sh + wave * 512;
  __bf16* lB = b_sh + wave * 512;

  for (int k0 = 0; k0 < 1024; k0 += 32) {
    __syncthreads();
    gload16(gA + k0, lA);
    gload16(gA + 64 * 1024 + k0, lA + 2048);
    gload16(gB + k0, lB);
    gload16(gB + 64 * 1024 + k0, lB + 2048);
    __syncthreads();
    bf16x8 af[4], bfr[4];
    #pragma unroll
    for (int i = 0; i < 4; ++i)
      af[i] = *(bf16x8*)&a_sh[(wm + i * 16 + r) * 32 + g * 8];
    #pragma unroll
    for (int j = 0; j < 4; ++j)
      bfr[j] = *(bf16x8*)&b_sh[(wn + j * 16 + r) * 32 + g * 8];
    #pragma unroll
    for (int i = 0; i < 4; ++i)
      #pragma unroll
      for (int j = 0; j < 4; ++j)
        acc[i][j] = MFMA16(af[i], bfr[j], acc[i][j]);
  }

  const int which = n0 >> 10;  // 0=Q 1=K 2=V
  const int bb = m0 >> 11;
  const int sbase = (m0 & 2047) + wm;
  #pragma unroll
  for (int j = 0; j < 4; ++j) {
    const int nc = n0 + wn + j * 16 + r;
    const float bv = bias[nc];
    const int hh = (nc & 1023) >> 6;
    const int d = nc & 63;
    #pragma unroll
    for (int i = 0; i < 4; ++i) {
      const int ss0 = sbase + i * 16 + g * 4;
      if (which == 0) {
        #pragma unroll
        for (int rr = 0; rr < 4; ++rr)
          Qb[((size_t)(bb * 16 + hh) * 2048 + ss0 + rr) * 64 + d] =
              (__bf16)((acc[i][j][rr] + bv) * SCQ);
      } else if (which == 1) {
        #pragma unroll
        for (int rr = 0; rr < 4; ++rr)
          Kb[((size_t)(bb * 16 + hh) * 2048 + ss0 + rr) * 64 + d] =
              (__bf16)(acc[i][j][rr] + bv);
      } else {
        bf16x4 vv;
        #pragma unroll
        for (int rr = 0; rr < 4; ++rr) vv[rr] = (__bf16)(acc[i][j][rr] + bv);
        *(bf16x4*)&Vt[((size_t)(bb * 16 + hh) * 64 + d) * 2048 + ss0] = vv;
      }
    }
  }
}

// proj: f32 out + bias; M=8192, N=1024
__global__ __launch_bounds__(256) void proj_gemm_b(
    const __bf16* __restrict__ A, const __bf16* __restrict__ Bt,
    const float* __restrict__ bias, float* __restrict__ out)
{
  __shared__ alignas(16) __bf16 a_sh[128 * 32];
  __shared__ alignas(16) __bf16 b_sh[128 * 32];
  const int n0 = blockIdx.x * 128, m0 = blockIdx.y * 128;
  const int t = threadIdx.x, wave = t >> 6, lane = t & 63;
  const int r = lane & 15, g = lane >> 4;
  const int wm = (wave >> 1) * 64, wn = (wave & 1) * 64;
  f32x4 acc[4][4] = {};

  const int srow = wave * 16 + (lane >> 2);
  const int scol = (lane & 3) * 8;
  const __bf16* gA = A + (size_t)(m0 + srow) * 1024 + scol;
  const __bf16* gB = Bt + (size_t)(n0 + srow) * 1024 + scol;
  __bf16* lA = a_sh + wave * 512;
  __bf16* lB = b_sh + wave * 512;

  for (int k0 = 0; k0 < 1024; k0 += 32) {
    __syncthreads();
    gload16(gA + k0, lA);
    gload16(gA + 64 * 1024 + k0, lA + 2048);
    gload16(gB + k0, lB);
    gload16(gB + 64 * 1024 + k0, lB + 2048);
    __syncthreads();
    bf16x8 af[4], bfr[4];
    #pragma unroll
    for (int i = 0; i < 4; ++i)
      af[i] = *(bf16x8*)&a_sh[(wm + i * 16 + r) * 32 + g * 8];
    #pragma unroll
    for (int j = 0; j < 4; ++j)
      bfr[j] = *(bf16x8*)&b_sh[(wn + j * 16 + r) * 32 + g * 8];
    #pragma unroll
    for (int i = 0; i < 4; ++i)
      #pragma unroll
      for (int j = 0; j < 4; ++j)
        acc[i][j] = MFMA16(af[i], bfr[j], acc[i][j]);
  }

  #pragma unroll
  for (int j = 0; j < 4; ++j) {
    const int nc = n0 + wn + j * 16 + r;
    const float bv = bias[nc];
    #pragma unroll
    for (int i = 0; i < 4; ++i)
      #pragma unroll
      for (int rr = 0; rr < 4; ++rr)
        out[(size_t)(m0 + wm + i * 16 + g * 4 + rr) * 1024 + nc] =
            acc[i][j][rr] + bv;
  }
}

// ---------------------------------------------------------------------------
// Flash attention, swapped-QK^T; Q pre-scaled by SCQ (exp2 domain).
// Block = 64 q-rows (2 waves x 32 q).  Defer-max (THR=6): common path has no
// per-score sub (C-in seeded with -m), no o-rescale.
// ---------------------------------------------------------------------------
__global__ __launch_bounds__(128) void attn_kernel(
    const __bf16* __restrict__ Q, const __bf16* __restrict__ K,
    const __bf16* __restrict__ Vt, __bf16* __restrict__ AO)
{
  __shared__ alignas(16) __bf16 k_sh[64][72];
  __shared__ alignas(16) __bf16 v_sh[64][72];
  const int b = blockIdx.z, h = blockIdx.y, qt = blockIdx.x;
  const int t = threadIdx.x, wave = t >> 6, lane = t & 63;
  const int r = lane & 15, g = lane >> 4;

  const __bf16* Qp = Q + (size_t)(b * 16 + h) * 2048 * 64;
  const __bf16* Kp = K + (size_t)(b * 16 + h) * 2048 * 64;
  const __bf16* Vp = Vt + (size_t)(b * 16 + h) * 64 * 2048;
  const int q0 = qt * 64 + wave * 32;

  bf16x8 qf[2][2];
  #pragma unroll
  for (int qh = 0; qh < 2; ++qh)
    #pragma unroll
    for (int hh = 0; hh < 2; ++hh)
      qf[qh][hh] =
          *(const bf16x8*)(Qp + (size_t)(q0 + qh * 16 + r) * 64 + hh * 32 + g * 8);

  float mrun[2] = {0.f, 0.f};
  float lrun[2] = {0.f, 0.f};
  f32x4 o[4][2] = {};

  const int krow = t >> 3, kcol = (t & 7) * 8;
  const int vch = t & 15, vrow = t >> 4;
  const int vcol = 32 * (vch >> 3) + 8 * (vch & 3) + 4 * ((vch >> 2) & 1);

  for (int k0 = 0; k0 < 2048; k0 += 64) {
    __syncthreads();
    #pragma unroll
    for (int p = 0; p < 4; ++p)
      *(bf16x8*)&k_sh[p * 16 + krow][kcol] =
          *(const bf16x8*)(Kp + (size_t)(k0 + p * 16 + krow) * 64 + kcol);
    #pragma unroll
    for (int p = 0; p < 8; ++p)
      *(bf16x4*)&v_sh[p * 8 + vrow][vcol] =
          *(const bf16x4*)(Vp + (size_t)(p * 8 + vrow) * 2048 + k0 + 4 * vch);
    __syncthreads();

    // --- QK^T, C seeded with -m so sacc = s' - m ---
    f32x4 sacc[4][2];
    const f32x4 seed0 = {-mrun[0], -mrun[0], -mrun[0], -mrun[0]};
    const f32x4 seed1 = {-mrun[1], -mrun[1], -mrun[1], -mrun[1]};
    __builtin_amdgcn_s_setprio(1);
    #pragma unroll
    for (int kt = 0; kt < 4; ++kt) {
      const bf16x8 kf0 = *(const bf16x8*)&k_sh[kt * 16 + r][g * 8];
      const bf16x8 kf1 = *(const bf16x8*)&k_sh[kt * 16 + r][32 + g * 8];
      f32x4 s0 = MFMA16(kf0, qf[0][0], seed0);
      s0 = MFMA16(kf1, qf[0][1], s0);
      sacc[kt][0] = s0;
      f32x4 s1 = MFMA16(kf0, qf[1][0], seed1);
      s1 = MFMA16(kf1, qf[1][1], s1);
      sacc[kt][1] = s1;
    }
    __builtin_amdgcn_s_setprio(0);

    // --- online softmax with defer-max ---
    bf16x8 pf[2][2];
    #pragma unroll
    for (int qh = 0; qh < 2; ++qh) {
      float tm = sacc[0][qh][0];
      #pragma unroll
      for (int kt = 0; kt < 4; ++kt)
        #pragma unroll
        for (int rr = 0; rr < 4; ++rr)
          tm = fmaxf(tm, sacc[kt][qh][rr]);
      tm = fmaxf(tm, __shfl_xor(tm, 16));
      tm = fmaxf(tm, __shfl_xor(tm, 32));

      float pv[4][4];
      float ps = 0.f;
      if (__any(tm > 6.0f)) {
        const float dl = fmaxf(tm, 0.f);
        const float al = exp2f(-dl);
        mrun[qh] += dl;
        #pragma unroll
        for (int kt = 0; kt < 4; ++kt)
          #pragma unroll
          for (int rr = 0; rr < 4; ++rr) {
            const float p = exp2f(sacc[kt][qh][rr] - dl);
            pv[kt][rr] = p;
            ps += p;
          }
        ps += __shfl_xor(ps, 16);
        ps += __shfl_xor(ps, 32);
        lrun[qh] = lrun[qh] * al + ps;
        #pragma unroll
        for (int dt = 0; dt < 4; ++dt)
          #pragma unroll
          for (int rr = 0; rr < 4; ++rr)
            o[dt][qh][rr] *= al;
      } else {
        #pragma unroll
        for (int kt = 0; kt < 4; ++kt)
          #pragma unroll
          for (int rr = 0; rr < 4; ++rr) {
            const float p = exp2f(sacc[kt][qh][rr]);
            pv[kt][rr] = p;
            ps += p;
          }
        ps += __shfl_xor(ps, 16);
        ps += __shfl_xor(ps, 32);
        lrun[qh] += ps;
      }
      // pack P lane-local in pi order: pf[c][j] = P[k = 32c+16(j>>2)+4g+(j&3)]
      #pragma unroll
      for (int c = 0; c < 2; ++c)
        #pragma unroll
        for (int j = 0; j < 8; ++j)
          pf[qh][c][j] = (__bf16)pv[2 * c + (j >> 2)][j & 3];
    }

    // --- PV ---
    __builtin_amdgcn_s_setprio(1);
    #pragma unroll
    for (int c = 0; c < 2; ++c)
      #pragma unroll
      for (int dt = 0; dt < 4; ++dt) {
        const bf16x8 vf = *(const bf16x8*)&v_sh[dt * 16 + r][c * 32 + g * 8];
        o[dt][0] = MFMA16(vf, pf[0][c], o[dt][0]);
        o[dt][1] = MFMA16(vf, pf[1][c], o[dt][1]);
      }
    __builtin_amdgcn_s_setprio(0);
  }

  #pragma unroll
  for (int qh = 0; qh < 2; ++qh) {
    const float inv = 1.0f / lrun[qh];
    const int ss = q0 + qh * 16 + r;
    #pragma unroll
    for (int dt = 0; dt < 4; ++dt) {
      bf16x4 ov;
      #pragma unroll
      for (int rr = 0; rr < 4; ++rr)
        ov[rr] = (__bf16)(o[dt][qh][rr] * inv);
      *(bf16x4*)&AO[((size_t)b * 2048 + ss) * 1024 + h * 64 + dt * 16 + 4 * g] = ov;
    }
  }
}

// ---------------------------------------------------------------------------
extern "C" void kernel_launch(void* const* d_in, const int* in_sizes, int n_in,
                              void* d_out, int out_size, void* d_ws, size_t ws_size,
                              hipStream_t stream) {
  (void)in_sizes; (void)n_in; (void)out_size; (void)ws_size;
  const float* x      = (const float*)d_in[0];
  const float* w_qkv  = (const float*)d_in[1];
  const float* b_qkv  = (const float*)d_in[2];
  const float* w_proj = (const float*)d_in[3];
  const float* b_proj = (const float*)d_in[4];
  float* out = (float*)d_out;

  char* ws = (char*)d_ws;
  const size_t E2 = (size_t)8192 * 1024 * 2;  // bytes per [8192][1024] bf16
  __bf16* Qb  = (__bf16*)(ws);
  __bf16* Kb  = (__bf16*)(ws + E2);
  __bf16* Vt  = (__bf16*)(ws + 2 * E2);
  __bf16* Xb  = (__bf16*)(ws + 3 * E2);
  __bf16* AO  = Xb;  // Xb dead after qkv_gemm_b; reuse for attention output
  __bf16* Wqt = (__bf16*)(ws + 4 * E2);
  __bf16* Wpt = (__bf16*)(ws + 4 * E2 + (size_t)3072 * 1024 * 2);

  conv_x<<<4096, 256, 0, stream>>>(x, Xb);
  conv_wt<<<dim3(48, 16), 256, 0, stream>>>(w_qkv, Wqt, 1024, 3072);
  conv_wt<<<dim3(16, 16), 256, 0, stream>>>(w_proj, Wpt, 1024, 1024);
  qkv_gemm_b<<<dim3(24, 64), 256, 0, stream>>>(Xb, Wqt, b_qkv, Qb, Kb, Vt);
  attn_kernel<<<dim3(32, 16, 4), 128, 0, stream>>>(Qb, Kb, Vt, AO);
  proj_gemm_b<<<dim3(8, 64), 256, 0, stream>>>(AO, Wpt, b_proj, out);
}

// Round 4
// 294.991 us; speedup vs baseline: 2.0552x; 1.0409x over previous
//
#include <hip/hip_runtime.h>
#include <hip/hip_bf16.h>
#include <cstdint>

typedef __attribute__((ext_vector_type(8))) __bf16 bf16x8;
typedef __attribute__((ext_vector_type(4))) __bf16 bf16x4;
typedef __attribute__((ext_vector_type(4))) float f32x4;

#define MFMA16(a, b, c) __builtin_amdgcn_mfma_f32_16x16x32_bf16(a, b, c, 0, 0, 0)

static constexpr float SCQ = 0.18033688f;  // (1/sqrt(64)) * log2(e)

__device__ __forceinline__ void gload16(const void* g, void* l) {
  __builtin_amdgcn_global_load_lds(
      (const __attribute__((address_space(1))) void*)g,
      (__attribute__((address_space(3))) void*)l, 16, 0, 0);
}

// ---------------------------------------------------------------------------
// conv_x: f32 [8192][1024] -> bf16 same layout
// ---------------------------------------------------------------------------
__global__ __launch_bounds__(256) void conv_x(const float* __restrict__ in,
                                              __bf16* __restrict__ out) {
  const size_t i = ((size_t)blockIdx.x * 256 + threadIdx.x) * 8;
  const float4 v0 = *(const float4*)(in + i);
  const float4 v1 = *(const float4*)(in + i + 4);
  bf16x8 o = {(__bf16)v0.x, (__bf16)v0.y, (__bf16)v0.z, (__bf16)v0.w,
              (__bf16)v1.x, (__bf16)v1.y, (__bf16)v1.z, (__bf16)v1.w};
  *(bf16x8*)(out + i) = o;
}

// ---------------------------------------------------------------------------
// conv_wt: W f32 [K][N] -> Wt bf16 [N][K]  (transpose via LDS tile)
// ---------------------------------------------------------------------------
__global__ __launch_bounds__(256) void conv_wt(const float* __restrict__ W,
                                               __bf16* __restrict__ Wt,
                                               int K, int N) {
  __shared__ float tile[64][65];
  const int nb = blockIdx.x * 64, kb = blockIdx.y * 64;
  const int t = threadIdx.x, tr = t >> 4, tc = t & 15;
  #pragma unroll
  for (int p = 0; p < 4; ++p) {
    const float4 v =
        *(const float4*)(W + (size_t)(kb + p * 16 + tr) * N + nb + tc * 4);
    tile[p * 16 + tr][tc * 4 + 0] = v.x;
    tile[p * 16 + tr][tc * 4 + 1] = v.y;
    tile[p * 16 + tr][tc * 4 + 2] = v.z;
    tile[p * 16 + tr][tc * 4 + 3] = v.w;
  }
  __syncthreads();
  #pragma unroll
  for (int p = 0; p < 4; ++p) {
    const int n = p * 16 + tr, kk = tc * 4;
    bf16x4 o = {(__bf16)tile[kk + 0][n], (__bf16)tile[kk + 1][n],
                (__bf16)tile[kk + 2][n], (__bf16)tile[kk + 3][n]};
    *(bf16x4*)(Wt + (size_t)(nb + n) * K + kb + kk) = o;
  }
}

// ---------------------------------------------------------------------------
// GEMM core (m97 structure): 128x128 tile, BK=32, global_load_lds w=16,
// linear LDS.  A bf16 [M][1024] row-major, Bt bf16 [N][1024] row-major (B^T).
// ---------------------------------------------------------------------------
__global__ __launch_bounds__(256) void qkv_gemm_b(
    const __bf16* __restrict__ A, const __bf16* __restrict__ Bt,
    const float* __restrict__ bias,
    __bf16* __restrict__ Qb, __bf16* __restrict__ Kb, __bf16* __restrict__ Vt)
{
  __shared__ alignas(16) __bf16 a_sh[128 * 32];
  __shared__ alignas(16) __bf16 b_sh[128 * 32];
  const int n0 = blockIdx.x * 128, m0 = blockIdx.y * 128;
  const int t = threadIdx.x, wave = t >> 6, lane = t & 63;
  const int r = lane & 15, g = lane >> 4;
  const int wm = (wave >> 1) * 64, wn = (wave & 1) * 64;
  f32x4 acc[4][4] = {};

  const int srow = wave * 16 + (lane >> 2);
  const int scol = (lane & 3) * 8;
  const __bf16* gA = A + (size_t)(m0 + srow) * 1024 + scol;
  const __bf16* gB = Bt + (size_t)(n0 + srow) * 1024 + scol;
  __bf16* lA = a_sh + wave * 512;
  __bf16* lB = b_sh + wave * 512;

  for (int k0 = 0; k0 < 1024; k0 += 32) {
    __syncthreads();
    gload16(gA + k0, lA);
    gload16(gA + 64 * 1024 + k0, lA + 2048);
    gload16(gB + k0, lB);
    gload16(gB + 64 * 1024 + k0, lB + 2048);
    __syncthreads();
    bf16x8 af[4], bfr[4];
    #pragma unroll
    for (int i = 0; i < 4; ++i)
      af[i] = *(bf16x8*)&a_sh[(wm + i * 16 + r) * 32 + g * 8];
    #pragma unroll
    for (int j = 0; j < 4; ++j)
      bfr[j] = *(bf16x8*)&b_sh[(wn + j * 16 + r) * 32 + g * 8];
    #pragma unroll
    for (int i = 0; i < 4; ++i)
      #pragma unroll
      for (int j = 0; j < 4; ++j)
        acc[i][j] = MFMA16(af[i], bfr[j], acc[i][j]);
  }

  const int which = n0 >> 10;  // 0=Q 1=K 2=V
  const int bb = m0 >> 11;
  const int sbase = (m0 & 2047) + wm;
  #pragma unroll
  for (int j = 0; j < 4; ++j) {
    const int nc = n0 + wn + j * 16 + r;
    const float bv = bias[nc];
    const int hh = (nc & 1023) >> 6;
    const int d = nc & 63;
    #pragma unroll
    for (int i = 0; i < 4; ++i) {
      const int ss0 = sbase + i * 16 + g * 4;
      if (which == 0) {
        #pragma unroll
        for (int rr = 0; rr < 4; ++rr)
          Qb[((size_t)(bb * 16 + hh) * 2048 + ss0 + rr) * 64 + d] =
              (__bf16)((acc[i][j][rr] + bv) * SCQ);
      } else if (which == 1) {
        #pragma unroll
        for (int rr = 0; rr < 4; ++rr)
          Kb[((size_t)(bb * 16 + hh) * 2048 + ss0 + rr) * 64 + d] =
              (__bf16)(acc[i][j][rr] + bv);
      } else {
        bf16x4 vv;
        #pragma unroll
        for (int rr = 0; rr < 4; ++rr) vv[rr] = (__bf16)(acc[i][j][rr] + bv);
        *(bf16x4*)&Vt[((size_t)(bb * 16 + hh) * 64 + d) * 2048 + ss0] = vv;
      }
    }
  }
}

__global__ __launch_bounds__(256) void proj_gemm_b(
    const __bf16* __restrict__ A, const __bf16* __restrict__ Bt,
    const float* __restrict__ bias, float* __restrict__ out)
{
  __shared__ alignas(16) __bf16 a_sh[128 * 32];
  __shared__ alignas(16) __bf16 b_sh[128 * 32];
  const int n0 = blockIdx.x * 128, m0 = blockIdx.y * 128;
  const int t = threadIdx.x, wave = t >> 6, lane = t & 63;
  const int r = lane & 15, g = lane >> 4;
  const int wm = (wave >> 1) * 64, wn = (wave & 1) * 64;
  f32x4 acc[4][4] = {};

  const int srow = wave * 16 + (lane >> 2);
  const int scol = (lane & 3) * 8;
  const __bf16* gA = A + (size_t)(m0 + srow) * 1024 + scol;
  const __bf16* gB = Bt + (size_t)(n0 + srow) * 1024 + scol;
  __bf16* lA = a_sh + wave * 512;
  __bf16* lB = b_sh + wave * 512;

  for (int k0 = 0; k0 < 1024; k0 += 32) {
    __syncthreads();
    gload16(gA + k0, lA);
    gload16(gA + 64 * 1024 + k0, lA + 2048);
    gload16(gB + k0, lB);
    gload16(gB + 64 * 1024 + k0, lB + 2048);
    __syncthreads();
    bf16x8 af[4], bfr[4];
    #pragma unroll
    for (int i = 0; i < 4; ++i)
      af[i] = *(bf16x8*)&a_sh[(wm + i * 16 + r) * 32 + g * 8];
    #pragma unroll
    for (int j = 0; j < 4; ++j)
      bfr[j] = *(bf16x8*)&b_sh[(wn + j * 16 + r) * 32 + g * 8];
    #pragma unroll
    for (int i = 0; i < 4; ++i)
      #pragma unroll
      for (int j = 0; j < 4; ++j)
        acc[i][j] = MFMA16(af[i], bfr[j], acc[i][j]);
  }

  #pragma unroll
  for (int j = 0; j < 4; ++j) {
    const int nc = n0 + wn + j * 16 + r;
    const float bv = bias[nc];
    #pragma unroll
    for (int i = 0; i < 4; ++i)
      #pragma unroll
      for (int rr = 0; rr < 4; ++rr)
        out[(size_t)(m0 + wm + i * 16 + g * 4 + rr) * 1024 + nc] =
            acc[i][j][rr] + bv;
  }
}

// ---------------------------------------------------------------------------
// Flash attention v3: 4 waves x 32 q = 128 q-rows/block, 1024 blocks.
// Double-buffered XOR-swizzled K/V LDS tiles, reg-staged (T14), ONE barrier
// per k-tile.  Swapped QK^T, seeded-C, defer-max, lane-local P (pi-permuted
// V layout).  XCD swizzle: all 16 q-tiles of one (b,h) on one XCD.
// ---------------------------------------------------------------------------
__global__ __launch_bounds__(256, 4) void attn_kernel(
    const __bf16* __restrict__ Q, const __bf16* __restrict__ K,
    const __bf16* __restrict__ Vt, __bf16* __restrict__ AO)
{
  __shared__ alignas(16) __bf16 k_sh[2][64 * 64];
  __shared__ alignas(16) __bf16 v_sh[2][64 * 64];

  // XCD swizzle: p%8 = head%8 so one head's 16 q-tiles share an XCD
  const int p = blockIdx.x;
  const int hd = (p & 7) + 8 * (p >> 7);   // 0..63 head linear = b*16+h
  const int qt = (p >> 3) & 15;
  const int b = hd >> 4, h = hd & 15;

  const int t = threadIdx.x, wave = t >> 6, lane = t & 63;
  const int r = lane & 15, g = lane >> 4;

  const __bf16* Qp = Q + (size_t)(b * 16 + h) * 2048 * 64;
  const __bf16* Kp = K + (size_t)(b * 16 + h) * 2048 * 64;
  const __bf16* Vp = Vt + (size_t)(b * 16 + h) * 64 * 2048;
  const int q0 = qt * 128 + wave * 32;

  // ---- staging geometry ----
  // K: thread t -> row kr = t>>2, two 16B chunks at byte cols (t&3)*16, +64
  const int kr = t >> 2;
  const int kce = (t & 3) * 8;                 // element col
  const int ksw = (kr & 7) << 4;
  const int kl0 = kr * 128 + (((t & 3) * 16) ^ ksw);
  const int kl1 = kr * 128 + ((((t & 3) * 16) + 64) ^ ksw);
  const __bf16* gK = Kp + (size_t)kr * 64 + kce;
  // V: thread t -> rows vr, vr+32; 16B at element col Gb = (t&7)*8
  //    pi layout: global 4-group G4 -> LDS col 32*(G4>>5)+8*((G4>>2)&3)+4*((G4>>4)&1)
  const int vr = t >> 3;
  const int Gb = (t & 7) * 8;
  const int La = 32 * (Gb >> 5) + 8 * ((Gb >> 2) & 3) + 4 * ((Gb >> 4) & 1);
  const int Gb2 = Gb + 4;
  const int Lb = 32 * (Gb2 >> 5) + 8 * ((Gb2 >> 2) & 3) + 4 * ((Gb2 >> 4) & 1);
  const int vsw = (vr & 7) << 4;
  const int vo0a = vr * 128 + ((2 * La) ^ vsw);
  const int vo0b = vr * 128 + ((2 * Lb) ^ vsw);
  const __bf16* gV = Vp + (size_t)vr * 2048 + Gb;

  // ---- Q fragments (pre-scaled by SCQ) ----
  bf16x8 qf[2][2];
  #pragma unroll
  for (int qh = 0; qh < 2; ++qh)
    #pragma unroll
    for (int hh = 0; hh < 2; ++hh)
      qf[qh][hh] =
          *(const bf16x8*)(Qp + (size_t)(q0 + qh * 16 + r) * 64 + hh * 32 + g * 8);

  float mrun[2] = {0.f, 0.f};
  float lrun[2] = {0.f, 0.f};
  f32x4 o[4][2] = {};

  // ---- staged registers ----
  bf16x8 kA, kB, vA, vB;
  #define LOADT(kk)                                                     \
    {                                                                   \
      kA = *(const bf16x8*)(gK + (size_t)(kk) * 64);                    \
      kB = *(const bf16x8*)(gK + (size_t)(kk) * 64 + 32);               \
      vA = *(const bf16x8*)(gV + (kk));                                 \
      vB = *(const bf16x8*)(gV + 65536 + (kk));                         \
    }
  #define STORET(bi)                                                    \
    {                                                                   \
      char* kbp = (char*)k_sh[bi];                                      \
      *(bf16x8*)(kbp + kl0) = kA;                                       \
      *(bf16x8*)(kbp + kl1) = kB;                                       \
      char* vbp = (char*)v_sh[bi];                                      \
      bf16x4 lo0 = {vA[0], vA[1], vA[2], vA[3]};                        \
      bf16x4 hi0 = {vA[4], vA[5], vA[6], vA[7]};                        \
      bf16x4 lo1 = {vB[0], vB[1], vB[2], vB[3]};                        \
      bf16x4 hi1 = {vB[4], vB[5], vB[6], vB[7]};                        \
      *(bf16x4*)(vbp + vo0a) = lo0;                                     \
      *(bf16x4*)(vbp + vo0b) = hi0;                                     \
      *(bf16x4*)(vbp + vo0a + 4096) = lo1;                              \
      *(bf16x4*)(vbp + vo0b + 4096) = hi1;                              \
    }

  // prologue: tile 0 -> buf 0
  LOADT(0);
  STORET(0);
  __syncthreads();

  const int swz = (r & 7) << 4;

  for (int t32 = 0; t32 < 32; ++t32) {
    const int cur = t32 & 1;
    if (t32 < 31) LOADT((t32 + 1) * 64);   // prefetch next tile into regs

    const char* kb = (const char*)k_sh[cur];
    const char* vb = (const char*)v_sh[cur];

    // --- QK^T (swapped), C seeded with -m ---
    f32x4 sacc[4][2];
    const f32x4 seed0 = {-mrun[0], -mrun[0], -mrun[0], -mrun[0]};
    const f32x4 seed1 = {-mrun[1], -mrun[1], -mrun[1], -mrun[1]};
    __builtin_amdgcn_s_setprio(1);
    #pragma unroll
    for (int kt = 0; kt < 4; ++kt) {
      const int rowb = (kt * 16 + r) * 128;
      const bf16x8 kf0 = *(const bf16x8*)(kb + rowb + ((g * 16) ^ swz));
      const bf16x8 kf1 = *(const bf16x8*)(kb + rowb + ((64 + g * 16) ^ swz));
      f32x4 s0 = MFMA16(kf0, qf[0][0], seed0);
      s0 = MFMA16(kf1, qf[0][1], s0);
      sacc[kt][0] = s0;
      f32x4 s1 = MFMA16(kf0, qf[1][0], seed1);
      s1 = MFMA16(kf1, qf[1][1], s1);
      sacc[kt][1] = s1;
    }
    __builtin_amdgcn_s_setprio(0);

    // --- online softmax with defer-max; P packed lane-local (pi order) ---
    bf16x8 pf[2][2];
    #pragma unroll
    for (int qh = 0; qh < 2; ++qh) {
      float tm = sacc[0][qh][0];
      #pragma unroll
      for (int kt = 0; kt < 4; ++kt)
        #pragma unroll
        for (int rr = 0; rr < 4; ++rr)
          tm = fmaxf(tm, sacc[kt][qh][rr]);
      tm = fmaxf(tm, __shfl_xor(tm, 16));
      tm = fmaxf(tm, __shfl_xor(tm, 32));

      float pv[4][4];
      float ps = 0.f;
      if (__any(tm > 6.0f)) {
        const float dl = fmaxf(tm, 0.f);
        const float al = exp2f(-dl);
        mrun[qh] += dl;
        #pragma unroll
        for (int kt = 0; kt < 4; ++kt)
          #pragma unroll
          for (int rr = 0; rr < 4; ++rr) {
            const float pp = exp2f(sacc[kt][qh][rr] - dl);
            pv[kt][rr] = pp;
            ps += pp;
          }
        ps += __shfl_xor(ps, 16);
        ps += __shfl_xor(ps, 32);
        lrun[qh] = lrun[qh] * al + ps;
        #pragma unroll
        for (int dt = 0; dt < 4; ++dt)
          #pragma unroll
          for (int rr = 0; rr < 4; ++rr)
            o[dt][qh][rr] *= al;
      } else {
        #pragma unroll
        for (int kt = 0; kt < 4; ++kt)
          #pragma unroll
          for (int rr = 0; rr < 4; ++rr) {
            const float pp = exp2f(sacc[kt][qh][rr]);
            pv[kt][rr] = pp;
            ps += pp;
          }
        ps += __shfl_xor(ps, 16);
        ps += __shfl_xor(ps, 32);
        lrun[qh] += ps;
      }
      #pragma unroll
      for (int c = 0; c < 2; ++c)
        #pragma unroll
        for (int j = 0; j < 8; ++j)
          pf[qh][c][j] = (__bf16)pv[2 * c + (j >> 2)][j & 3];
    }

    // --- PV ---
    __builtin_amdgcn_s_setprio(1);
    #pragma unroll
    for (int c = 0; c < 2; ++c)
      #pragma unroll
      for (int dt = 0; dt < 4; ++dt) {
        const bf16x8 vf =
            *(const bf16x8*)(vb + (dt * 16 + r) * 128 + ((c * 64 + g * 16) ^ swz));
        o[dt][0] = MFMA16(vf, pf[0][c], o[dt][0]);
        o[dt][1] = MFMA16(vf, pf[1][c], o[dt][1]);
      }
    __builtin_amdgcn_s_setprio(0);

    if (t32 < 31) STORET(cur ^ 1);   // waits vmcnt via reg deps
    __syncthreads();
  }
  #undef LOADT
  #undef STORET

  // --- epilogue: normalize, write AO[b, s, h*64+d] (d = dt*16+4g+rr) ---
  #pragma unroll
  for (int qh = 0; qh < 2; ++qh) {
    const float inv = 1.0f / lrun[qh];
    const int ss = q0 + qh * 16 + r;
    #pragma unroll
    for (int dt = 0; dt < 4; ++dt) {
      bf16x4 ov;
      #pragma unroll
      for (int rr = 0; rr < 4; ++rr)
        ov[rr] = (__bf16)(o[dt][qh][rr] * inv);
      *(bf16x4*)&AO[((size_t)b * 2048 + ss) * 1024 + h * 64 + dt * 16 + 4 * g] = ov;
    }
  }
}

// ---------------------------------------------------------------------------
extern "C" void kernel_launch(void* const* d_in, const int* in_sizes, int n_in,
                              void* d_out, int out_size, void* d_ws, size_t ws_size,
                              hipStream_t stream) {
  (void)in_sizes; (void)n_in; (void)out_size; (void)ws_size;
  const float* x      = (const float*)d_in[0];
  const float* w_qkv  = (const float*)d_in[1];
  const float* b_qkv  = (const float*)d_in[2];
  const float* w_proj = (const float*)d_in[3];
  const float* b_proj = (const float*)d_in[4];
  float* out = (float*)d_out;

  char* ws = (char*)d_ws;
  const size_t E2 = (size_t)8192 * 1024 * 2;  // bytes per [8192][1024] bf16
  __bf16* Qb  = (__bf16*)(ws);
  __bf16* Kb  = (__bf16*)(ws + E2);
  __bf16* Vt  = (__bf16*)(ws + 2 * E2);
  __bf16* Xb  = (__bf16*)(ws + 3 * E2);
  __bf16* AO  = Xb;  // Xb dead after qkv_gemm_b; reuse for attention output
  __bf16* Wqt = (__bf16*)(ws + 4 * E2);
  __bf16* Wpt = (__bf16*)(ws + 4 * E2 + (size_t)3072 * 1024 * 2);

  conv_x<<<4096, 256, 0, stream>>>(x, Xb);
  conv_wt<<<dim3(48, 16), 256, 0, stream>>>(w_qkv, Wqt, 1024, 3072);
  conv_wt<<<dim3(16, 16), 256, 0, stream>>>(w_proj, Wpt, 1024, 1024);
  qkv_gemm_b<<<dim3(24, 64), 256, 0, stream>>>(Xb, Wqt, b_qkv, Qb, Kb, Vt);
  attn_kernel<<<1024, 256, 0, stream>>>(Qb, Kb, Vt, AO);
  proj_gemm_b<<<dim3(8, 64), 256, 0, stream>>>(AO, Wpt, b_proj, out);
}